// Round 9
// baseline (1166.824 us; speedup 1.0000x reference)
//
#include <hip/hip_runtime.h>
#include <cstdint>
#include <cstddef>

// ---------------------------------------------------------------------------
// SpikingCoreFlow: bit-exact replication of the JAX reference on MI355X.
//
// Dims: B=128, D_in=1024, n_cores=64, N=256, A=256, n_out=10, cycles=32,
// pool_width = 17410.
//
// Pool "Pb" (bytes, rows of 128 = B):
//   rows [0, 32768)        : spikes, row = t*1024 + d
//   rows [32768, 49152)    : buffer ping (A), row = 32768 + c*256 + n
//   rows [49152, 65536)    : buffer pong (B)
//   row 65536 / 65537      : zeros / ones columns
// Cycle t reads parity A if t even, writes the other.
//
// Exactness (verified R2-R8, absmax == 0.0):
//  - threefry2x32 with jax_threefry_partitionable=True semantics.
//  - einsum 'cna,bca->cbn' = single ascending-a fused-FMA chain from 0 per
//    (c,b,n); memb += E is one more rounded add. v_pk_fma_f32 = 2 independent
//    IEEE FMAs; mask operands are exactly {0.0f,1.0f} -> chain bit-exact.
//
// Perf journal (per core dispatch; VALU floor 6.8us, VMEM-return@Bt=8 6.8us):
//  R3/R4 ~20us: wave-uniform weights -> s_load serialization. SMEM won't pipe.
//  R5 ~26us: per-lane weights, Bt=4 -> 2MB/CU VMEM return (13.6us floor).
//  R6 ~82us: 1 wave/SIMD exposed every stall; SALU mask machinery 2x VALU.
//  R7/R8 ~22us: 2 uniform ds_read_b128/a/wave = 8w*256a*2*~10cy = 41K cy on
//    the ONE per-CU DS pipe (broadcast still fans out 1KB to VGPRs) = ~17us.
//    DS is the plateau across R3-R8.
//  R9: masks leave the DS pipe. Phase 1 bit-packs 256a x 16b masks into
//    2x64 LDS words; hot loop reads ONE ds_read_b64 per 8-a chunk, moves the
//    bits to SGPRs via readfirstlane, and builds {0,1} v2f operands with
//    SALU (hidden under VALU). DS: 512 -> 32 instr/wave. Weights unchanged
//    (per-lane dwordx2, chunk-8 named double-buffer).
//  R8 lesson kept: graph = kernels only (init_kernel, no hipMemsetAsync).
// ---------------------------------------------------------------------------

#define N_CORES   64
#define NN        256
#define AA        256
#define BB        128
#define DIN       1024
#define NOUT      10
#define CYCLES    32
#define ROW_SPK   0u
#define ROW_A     32768u
#define ROW_B     49152u
#define ROW_ZERO  65536u
#define ROW_ONE   65537u

typedef float v2f __attribute__((ext_vector_type(2)));

__device__ __forceinline__ void tf_round(uint32_t& x0, uint32_t& x1, int r) {
    x0 += x1;
    x1 = (x1 << r) | (x1 >> (32 - r));
    x1 ^= x0;
}

__device__ __forceinline__ void threefry2x32(uint32_t k0, uint32_t k1,
                                             uint32_t c0, uint32_t c1,
                                             uint32_t& o0, uint32_t& o1) {
    uint32_t ks2 = k0 ^ k1 ^ 0x1BD11BDAu;
    uint32_t x0 = c0 + k0, x1 = c1 + k1;
    tf_round(x0,x1,13); tf_round(x0,x1,15); tf_round(x0,x1,26); tf_round(x0,x1,6);
    x0 += k1; x1 += ks2 + 1u;
    tf_round(x0,x1,17); tf_round(x0,x1,29); tf_round(x0,x1,16); tf_round(x0,x1,24);
    x0 += ks2; x1 += k0 + 2u;
    tf_round(x0,x1,13); tf_round(x0,x1,15); tf_round(x0,x1,26); tf_round(x0,x1,6);
    x0 += k0; x1 += k1 + 3u;
    tf_round(x0,x1,17); tf_round(x0,x1,29); tf_round(x0,x1,16); tf_round(x0,x1,24);
    x0 += k1; x1 += ks2 + 4u;
    tf_round(x0,x1,13); tf_round(x0,x1,15); tf_round(x0,x1,26); tf_round(x0,x1,6);
    x0 += ks2; x1 += k0 + 5u;
    o0 = x0; o1 = x1;
}

// All launch-time state init in ONE kernel (graph stays kernels-only):
__global__ void init_kernel(unsigned char* __restrict__ Pb,
                            float* __restrict__ memb,
                            float* __restrict__ out) {
    int idx = blockIdx.x * 256 + threadIdx.x;       // 2048 blocks -> 524288
    float4 z = {0.0f, 0.0f, 0.0f, 0.0f};
    *(float4*)(memb + (size_t)idx * 4) = z;                         // 8 MiB
    *(uint32_t*)(Pb + (size_t)ROW_A * 128 + (size_t)idx * 4) = 0u;  // 2 MiB
    if (idx < 32)
        *(uint32_t*)(Pb + (size_t)ROW_ZERO * 128 + idx * 4) = 0u;
    else if (idx < 64)
        *(uint32_t*)(Pb + (size_t)ROW_ONE * 128 + (idx - 32) * 4) = 0x01010101u;
    if (idx < BB * NOUT)
        out[idx] = 0.0f;
}

__global__ void spikes_kernel(const float* __restrict__ x,
                              unsigned char* __restrict__ Pb) {
    __shared__ unsigned char S[32 * 132];
    int bx  = blockIdx.x;        // 1024 = 32 t * 32 dblk
    int t   = bx >> 5;
    int d0  = (bx & 31) * 32;
    int tid = threadIdx.x;

    uint32_t k0, k1;
    threefry2x32(0u, 42u, 0u, (uint32_t)t, k0, k1);   // keys[t] = (w0, w1)

    #pragma unroll
    for (int k = 0; k < 16; ++k) {
        int e  = tid + k * 256;      // 0..4095 = 128 bb * 32 dl
        int bb = e >> 5;
        int dl = e & 31;
        int d  = d0 + dl;
        uint32_t f = (uint32_t)(bb * 1024 + d);
        uint32_t y0, y1;
        threefry2x32(k0, k1, 0u, f, y0, y1);
        uint32_t bits = y0 ^ y1;                      // xor-fold
        float u = __uint_as_float((bits >> 9) | 0x3f800000u) - 1.0f;
        S[dl * 132 + bb] = (u < x[bb * 1024 + d]) ? 1 : 0;
    }
    __syncthreads();

    int dl = tid >> 3;
    int bg = tid & 7;
    const uint32_t* Srow = (const uint32_t*)(S + dl * 132);
    uint4 v;
    v.x = Srow[bg * 4 + 0]; v.y = Srow[bg * 4 + 1];
    v.z = Srow[bg * 4 + 2]; v.w = Srow[bg * 4 + 3];
    size_t row = (size_t)t * 1024 + d0 + dl;
    *(uint4*)(Pb + row * 128 + bg * 16) = v;
}

// WT[c][a][n] = W[c][n][a]
__global__ void wt_kernel(const float* __restrict__ W, float* __restrict__ WT) {
    __shared__ float T[32][33];
    int bx = blockIdx.x;            // 4096 = 64 c * 8 tn * 8 ta
    int c  = bx >> 6;
    int tn = (bx >> 3) & 7;
    int ta = bx & 7;
    int tid = threadIdx.x;
    int r  = tid >> 3;
    int q4 = (tid & 7) * 4;

    const float* src = W + (size_t)c * 65536 + (size_t)(tn * 32 + r) * 256 + ta * 32 + q4;
    float4 v = *(const float4*)src;
    T[r][q4 + 0] = v.x; T[r][q4 + 1] = v.y; T[r][q4 + 2] = v.z; T[r][q4 + 3] = v.w;
    __syncthreads();

    float4 o;
    o.x = T[q4 + 0][r]; o.y = T[q4 + 1][r]; o.z = T[q4 + 2][r]; o.w = T[q4 + 3][r];
    float* dst = WT + (size_t)c * 65536 + (size_t)(ta * 32 + r) * 256 + tn * 32 + q4;
    *(float4*)dst = o;
}

__global__ void offtab_kernel(const int* __restrict__ axon,
                              const int* __restrict__ outsrc,
                              uint32_t* __restrict__ off_tab,
                              uint32_t* __restrict__ out_off) {
    int bx = blockIdx.x;
    int tid = threadIdx.x;
    if (bx < 2048) {
        int idx = bx * 256 + tid;          // [t][c*256+a]
        int t   = idx >> 14;
        int ca  = idx & 16383;
        int j   = axon[ca];
        uint32_t row;
        if (j < 1024)        row = (uint32_t)(t * 1024 + j);
        else if (j < 17408)  row = (((t & 1) == 0) ? ROW_A : ROW_B) + (uint32_t)(j - 1024);
        else                 row = (j == 17408) ? ROW_ZERO : ROW_ONE;
        off_tab[idx] = row * 128u;
    } else {
        for (int idx = tid; idx < CYCLES * NOUT; idx += 256) {
            int t = idx / NOUT, o = idx % NOUT;
            int j = outsrc[o];
            uint32_t row;
            if (j < 1024)        row = (uint32_t)(t * 1024 + j);
            else if (j < 17408)  row = (((t & 1) == 0) ? ROW_B : ROW_A) + (uint32_t)(j - 1024);
            else                 row = (j == 17408) ? ROW_ZERO : ROW_ONE;
            out_off[idx] = row * 128u;
        }
    }
}

// One cycle. 512 blocks x 256 thr (4 waves) = (c, bg of 16 b), XCD-swizzled.
// Wave w: b-oct = (w&1), n-half = (w>>1)*128; lane owns an n-pair.
// Phase 1: bit-pack 256a x 16b masks -> MW[2][64] words (1 byte store/thread).
// Hot loop per 8-a chunk: 8 per-lane dwordx2 weight loads (named dbuf) +
// 1 ds_read_b64 -> readfirstlane -> SGPR bits; per a: build 4 {0,1} v2f
// operands with SALU, 8 v_pk_fma_f32. DS pipe ~32 instr/wave total.
__global__ __launch_bounds__(256, 2) void core_kernel(
    const unsigned char* __restrict__ Pb,
    unsigned char* __restrict__ Pw,
    const float* __restrict__ WT,
    const uint32_t* __restrict__ off_t,
    float* __restrict__ memb,
    const float* __restrict__ thresholds,
    uint32_t wbyte_base,
    const uint32_t* __restrict__ out_off_prev,
    float* __restrict__ d_out,
    int do_out)
{
    __shared__ uint32_t MW[2][64];      // [b-oct][a-quad word]

    int tid = threadIdx.x;
    int bx  = blockIdx.x;

    // fused out-update for the PREVIOUS cycle (reads current READ parity —
    // never written by this kernel)
    if (do_out && bx == 0 && tid < BB) {
        #pragma unroll
        for (int o = 0; o < NOUT; ++o) {
            uint32_t off = out_off_prev[o];
            d_out[tid * NOUT + o] += (float)Pb[off + (uint32_t)tid];
        }
    }

    // decode: 512 = 8 xcd * 8 c-local * 8 bg  (c grouped per XCD: 2MB WT/L2)
    int c     = (bx & 7) * 8 + ((bx >> 3) & 7);
    int bg    = bx >> 6;               // 0..7
    int b0blk = bg * 16;

    // ---- Phase 1: gather + bit-pack masks (thread = a) ----
    {
        uint32_t off = off_t[c * 256 + tid];            // coalesced
        uint4 v = *(const uint4*)(Pb + off + (uint32_t)b0blk);
        const unsigned char* pb = (const unsigned char*)&v;
        uint32_t lo = 0, hi = 0;
        #pragma unroll
        for (int j = 0; j < 8; ++j) {
            lo |= (uint32_t)(pb[j] & 1u) << j;
            hi |= (uint32_t)(pb[8 + j] & 1u) << j;
        }
        ((unsigned char*)MW[0])[tid] = (unsigned char)lo;   // byte a of oct 0
        ((unsigned char*)MW[1])[tid] = (unsigned char)hi;   // byte a of oct 1
    }
    __syncthreads();

    int lane = tid & 63;
    int wid  = __builtin_amdgcn_readfirstlane(tid >> 6);
    int bo   = wid & 1;                // b-oct within the 16
    int nh   = wid >> 1;               // n-half
    int b0   = b0blk + bo * 8;
    int n0   = nh * 128;

    const float* wt = WT + (size_t)c * 65536 + n0 + lane * 2;  // +a*256/iter
    const uint32_t* mwp = MW[bo];

    v2f acc0[4], acc1[4];              // nj=0/1, bp=0..3 (b pairs)
    #pragma unroll
    for (int bp = 0; bp < 4; ++bp) { acc0[bp] = (v2f){0.f, 0.f}; acc1[bp] = (v2f){0.f, 0.f}; }

    v2f wA[8], wB[8];
    uint32_t bAlo, bAhi, bBlo, bBhi;

#define LOADW(Wb, ch)                                                         \
    { const float* p_ = wt + (size_t)(ch) * 8 * 256;                          \
      _Pragma("unroll")                                                       \
      for (int i_ = 0; i_ < 8; ++i_)                                          \
          Wb[i_] = *(const v2f*)(p_ + (size_t)i_ * 256); }

#define RDBITS(lo_, hi_, ch)                                                  \
    { uint2 t_ = *(const uint2*)(mwp + (ch) * 2);                             \
      lo_ = (uint32_t)__builtin_amdgcn_readfirstlane((int)t_.x);              \
      hi_ = (uint32_t)__builtin_amdgcn_readfirstlane((int)t_.y); }

#define FMACH(Wb, blo_, bhi_)                                                 \
    { _Pragma("unroll")                                                       \
      for (int i_ = 0; i_ < 8; ++i_) {                                        \
          uint32_t byt_ = (((i_ < 4) ? (blo_) : (bhi_)) >> (8 * (i_ & 3))) & 0xFFu; \
          v2f w_  = Wb[i_];                                                   \
          v2f w0_ = {w_.x, w_.x};                                             \
          v2f w1_ = {w_.y, w_.y};                                             \
          _Pragma("unroll")                                                   \
          for (int bp_ = 0; bp_ < 4; ++bp_) {                                 \
              uint32_t m0_ = (0u - ((byt_ >> (2 * bp_)) & 1u)) & 0x3F800000u; \
              uint32_t m1_ = (0u - ((byt_ >> (2 * bp_ + 1)) & 1u)) & 0x3F800000u; \
              v2f m2_ = __builtin_bit_cast(v2f,                               \
                          ((uint64_t)m1_ << 32) | (uint64_t)m0_);             \
              acc0[bp_] = __builtin_elementwise_fma(w0_, m2_, acc0[bp_]);     \
              acc1[bp_] = __builtin_elementwise_fma(w1_, m2_, acc1[bp_]);     \
          }                                                                   \
      } }

    RDBITS(bAlo, bAhi, 0);
    LOADW(wA, 0);
    for (int ch = 0; ch < 32; ch += 2) {
        RDBITS(bBlo, bBhi, ch + 1);
        LOADW(wB, ch + 1);
        FMACH(wA, bAlo, bAhi);
        if (ch + 2 < 32) {
            RDBITS(bAlo, bAhi, ch + 2);
            LOADW(wA, ch + 2);
        }
        FMACH(wB, bBlo, bBhi);
    }
#undef LOADW
#undef RDBITS
#undef FMACH

    // ---- Epilogue: memb RMW + fired bytes (2 n-rows x 8 b per lane) ----
    float thr = thresholds[c];
    #pragma unroll
    for (int nj = 0; nj < 2; ++nj) {
        int n = n0 + 2 * lane + nj;
        size_t rowb = (size_t)(c * 256 + n) * 128 + b0;
        const v2f* accp = (nj == 0) ? acc0 : acc1;
        float4 m0 = *(const float4*)(memb + rowb);
        float4 m1 = *(const float4*)(memb + rowb + 4);
        float vv[8];
        vv[0] = m0.x + accp[0].x;  vv[1] = m0.y + accp[0].y;
        vv[2] = m0.z + accp[1].x;  vv[3] = m0.w + accp[1].y;
        vv[4] = m1.x + accp[2].x;  vv[5] = m1.y + accp[2].y;
        vv[6] = m1.z + accp[3].x;  vv[7] = m1.w + accp[3].y;
        uint32_t flo = 0, fhi = 0;
        float st[8];
        #pragma unroll
        for (int k = 0; k < 8; ++k) {
            bool f = vv[k] > thr;
            st[k] = f ? 0.0f : vv[k];
            if (k < 4) flo |= (f ? 1u : 0u) << (8 * k);
            else       fhi |= (f ? 1u : 0u) << (8 * (k - 4));
        }
        float4 s0 = {st[0], st[1], st[2], st[3]};
        float4 s1 = {st[4], st[5], st[6], st[7]};
        *(float4*)(memb + rowb)     = s0;
        *(float4*)(memb + rowb + 4) = s1;
        uint2 fb = {flo, fhi};
        *(uint2*)(Pw + wbyte_base + rowb) = fb;
    }
}

__global__ void tail_kernel(const unsigned char* __restrict__ Pb,
                            const uint32_t* __restrict__ out_off31,
                            float* __restrict__ d_out) {
    int tid = threadIdx.x;
    if (tid < BB) {
        #pragma unroll
        for (int o = 0; o < NOUT; ++o) {
            uint32_t off = out_off31[o];
            d_out[tid * NOUT + o] += (float)Pb[off + (uint32_t)tid];
        }
    }
}

extern "C" void kernel_launch(void* const* d_in, const int* in_sizes, int n_in,
                              void* d_out_, int out_size, void* d_ws, size_t ws_size,
                              hipStream_t stream) {
    const float* x          = (const float*)d_in[0];
    const float* W          = (const float*)d_in[1];
    const float* thresholds = (const float*)d_in[2];
    const int*   axon       = (const int*)d_in[3];
    const int*   outsrc     = (const int*)d_in[4];
    // d_in[5] = cycles; fixed instance -> 32.

    if (ws_size < (size_t)45 * 1024 * 1024) return;

    unsigned char* ws      = (unsigned char*)d_ws;
    unsigned char* Pb      = ws;                                    // 8.4 MB
    float*         WT      = (float*)(ws + (size_t)(16u << 20));    // 16 MiB
    uint32_t*      off_tab = (uint32_t*)(ws + (size_t)(32u << 20)); // 2 MiB
    uint32_t*      out_off = (uint32_t*)(ws + (size_t)(32u << 20) + 2u * 1024u * 1024u);
    float*         memb    = (float*)(ws + (size_t)(36u << 20));    // 8 MiB
    float*         out     = (float*)d_out_;

    init_kernel<<<2048, 256, 0, stream>>>(Pb, memb, out);
    spikes_kernel<<<1024, 256, 0, stream>>>(x, Pb);
    wt_kernel<<<4096, 256, 0, stream>>>(W, WT);
    offtab_kernel<<<2049, 256, 0, stream>>>(axon, outsrc, off_tab, out_off);

    for (int t = 0; t < CYCLES; ++t) {
        uint32_t wrow = ((t & 1) == 0) ? ROW_B : ROW_A;   // write parity
        const uint32_t* oprev = out_off + (t > 0 ? (t - 1) * NOUT : 0);
        core_kernel<<<512, 256, 0, stream>>>(
            Pb, Pb, WT, off_tab + (size_t)t * 16384, memb, thresholds,
            wrow * 128u, oprev, out, t > 0 ? 1 : 0);
    }
    tail_kernel<<<1, 128, 0, stream>>>(Pb, out_off + 31 * NOUT, out);
}

// Round 10
// 1026.321 us; speedup vs baseline: 1.1369x; 1.1369x over previous
//
#include <hip/hip_runtime.h>
#include <cstdint>
#include <cstddef>

// ---------------------------------------------------------------------------
// SpikingCoreFlow: bit-exact replication of the JAX reference on MI355X.
//
// Dims: B=128, D_in=1024, n_cores=64, N=256, A=256, n_out=10, cycles=32,
// pool_width = 17410.
//
// Pool "Pb" (bytes, rows of 128 = B): spikes rows [0,32768) = t*1024+d;
// buffer ping A [32768,49152), pong B [49152,65536); zeros 65536; ones 65537.
// Cycle t reads parity A if t even, writes the other.
//
// Exactness (verified R2-R9, absmax == 0.0):
//  - threefry2x32, jax_threefry_partitionable=True semantics.
//  - einsum = single ascending-a fused-FMA chain from 0 per (c,b,n); memb+=E
//    is one more rounded add. Mask operands are exactly {0.0f,1.0f}.
//
// Perf journal (core dispatch):
//  R3/R4 ~20us: ds+smem on lgkm -> lgkmcnt(0) per a -> K$ latency serial.
//  R5 ~26us: Bt=4 -> 2MB/CU VMEM return.   R6 ~82us: 1 wave/SIMD + VALU bloat.
//  R7/R8 ~22us: 2 uniform ds_read_b128/a/wave x 12cy x 8w = 49K cy: the DS
//    pipe wastes 64x on broadcast reads. R9 ~35us: SGPR->v2f mask build
//    materialized v_movs (pk_fma takes only one 32b scalar).
//  R10: masks = SCALAR operand (s_load from global float table M), weights =
//    per-lane VMEM (vmcnt pipelines). v_fmac_f32 acc, s_m, v_w. Zero DS.
//    M[t+1] built in-flight: epilogue inverse-scatters fired floats
//    (~0.94 consumers/row, static inverse table), filler blocks write
//    spike-axon entries, setup prefills consts. No pack kernels.
//  R8 lesson kept: graph = kernels only (init_kernel, no hipMemsetAsync).
// ---------------------------------------------------------------------------

#define N_CORES   64
#define NN        256
#define AA        256
#define BB        128
#define DIN       1024
#define NOUT      10
#define CYCLES    32
#define ROW_SPK   0u
#define ROW_A     32768u
#define ROW_B     49152u
#define ROW_ZERO  65536u
#define ROW_ONE   65537u

typedef float v2f __attribute__((ext_vector_type(2)));

__device__ __forceinline__ void tf_round(uint32_t& x0, uint32_t& x1, int r) {
    x0 += x1;
    x1 = (x1 << r) | (x1 >> (32 - r));
    x1 ^= x0;
}

__device__ __forceinline__ void threefry2x32(uint32_t k0, uint32_t k1,
                                             uint32_t c0, uint32_t c1,
                                             uint32_t& o0, uint32_t& o1) {
    uint32_t ks2 = k0 ^ k1 ^ 0x1BD11BDAu;
    uint32_t x0 = c0 + k0, x1 = c1 + k1;
    tf_round(x0,x1,13); tf_round(x0,x1,15); tf_round(x0,x1,26); tf_round(x0,x1,6);
    x0 += k1; x1 += ks2 + 1u;
    tf_round(x0,x1,17); tf_round(x0,x1,29); tf_round(x0,x1,16); tf_round(x0,x1,24);
    x0 += ks2; x1 += k0 + 2u;
    tf_round(x0,x1,13); tf_round(x0,x1,15); tf_round(x0,x1,26); tf_round(x0,x1,6);
    x0 += k0; x1 += k1 + 3u;
    tf_round(x0,x1,17); tf_round(x0,x1,29); tf_round(x0,x1,16); tf_round(x0,x1,24);
    x0 += k1; x1 += ks2 + 4u;
    tf_round(x0,x1,13); tf_round(x0,x1,15); tf_round(x0,x1,26); tf_round(x0,x1,6);
    x0 += ks2; x1 += k0 + 5u;
    o0 = x0; o1 = x1;
}

// All launch-time state init in ONE kernel (graph stays kernels-only).
__global__ void init_kernel(unsigned char* __restrict__ Pb,
                            float* __restrict__ memb,
                            float* __restrict__ M0,
                            uint32_t* __restrict__ inv_cnt,
                            uint32_t* __restrict__ spike_cnt,
                            float* __restrict__ out) {
    int idx = blockIdx.x * 256 + threadIdx.x;       // 2048 blocks -> 524288
    float4 z = {0.0f, 0.0f, 0.0f, 0.0f};
    *(float4*)(memb + (size_t)idx * 4) = z;                         // 8 MiB
    *(float4*)(M0   + (size_t)idx * 4) = z;                         // 8 MiB
    *(uint32_t*)(Pb + (size_t)ROW_A * 128 + (size_t)idx * 4) = 0u;  // 2 MiB
    if (idx < 32)
        *(uint32_t*)(Pb + (size_t)ROW_ZERO * 128 + idx * 4) = 0u;
    else if (idx < 64)
        *(uint32_t*)(Pb + (size_t)ROW_ONE * 128 + (idx - 32) * 4) = 0x01010101u;
    if (idx < BB * NOUT) out[idx] = 0.0f;
    if (idx < 16384) inv_cnt[idx] = 0u;
    if (idx == 16384) *spike_cnt = 0u;
}

__global__ void spikes_kernel(const float* __restrict__ x,
                              unsigned char* __restrict__ Pb) {
    __shared__ unsigned char S[32 * 132];
    int bx  = blockIdx.x;        // 1024 = 32 t * 32 dblk
    int t   = bx >> 5;
    int d0  = (bx & 31) * 32;
    int tid = threadIdx.x;

    uint32_t k0, k1;
    threefry2x32(0u, 42u, 0u, (uint32_t)t, k0, k1);   // keys[t] = (w0, w1)

    #pragma unroll
    for (int k = 0; k < 16; ++k) {
        int e  = tid + k * 256;      // 0..4095 = 128 bb * 32 dl
        int bb = e >> 5;
        int dl = e & 31;
        int d  = d0 + dl;
        uint32_t f = (uint32_t)(bb * 1024 + d);
        uint32_t y0, y1;
        threefry2x32(k0, k1, 0u, f, y0, y1);
        uint32_t bits = y0 ^ y1;                      // xor-fold
        float u = __uint_as_float((bits >> 9) | 0x3f800000u) - 1.0f;
        S[dl * 132 + bb] = (u < x[bb * 1024 + d]) ? 1 : 0;
    }
    __syncthreads();

    int dl = tid >> 3;
    int bg = tid & 7;
    const uint32_t* Srow = (const uint32_t*)(S + dl * 132);
    uint4 v;
    v.x = Srow[bg * 4 + 0]; v.y = Srow[bg * 4 + 1];
    v.z = Srow[bg * 4 + 2]; v.w = Srow[bg * 4 + 3];
    size_t row = (size_t)t * 1024 + d0 + dl;
    *(uint4*)(Pb + row * 128 + bg * 16) = v;
}

// WT[c][a][n] = W[c][n][a]
__global__ void wt_kernel(const float* __restrict__ W, float* __restrict__ WT) {
    __shared__ float T[32][33];
    int bx = blockIdx.x;            // 4096 = 64 c * 8 tn * 8 ta
    int c  = bx >> 6;
    int tn = (bx >> 3) & 7;
    int ta = bx & 7;
    int tid = threadIdx.x;
    int r  = tid >> 3;
    int q4 = (tid & 7) * 4;

    const float* src = W + (size_t)c * 65536 + (size_t)(tn * 32 + r) * 256 + ta * 32 + q4;
    float4 v = *(const float4*)src;
    T[r][q4 + 0] = v.x; T[r][q4 + 1] = v.y; T[r][q4 + 2] = v.z; T[r][q4 + 3] = v.w;
    __syncthreads();

    float4 o;
    o.x = T[q4 + 0][r]; o.y = T[q4 + 1][r]; o.z = T[q4 + 2][r]; o.w = T[q4 + 3][r];
    float* dst = WT + (size_t)c * 65536 + (size_t)(ta * 32 + r) * 256 + tn * 32 + q4;
    *(float4*)dst = o;
}

// out_off[t][o] = byte offset of pool2 row for out_src at cycle t (WRITE parity)
__global__ void outoff_kernel(const int* __restrict__ outsrc,
                              uint32_t* __restrict__ out_off) {
    int tid = threadIdx.x;
    for (int idx = tid; idx < CYCLES * NOUT; idx += 256) {
        int t = idx / NOUT, o = idx % NOUT;
        int j = outsrc[o];
        uint32_t row;
        if (j < 1024)        row = (uint32_t)(t * 1024 + j);
        else if (j < 17408)  row = (((t & 1) == 0) ? ROW_B : ROW_A) + (uint32_t)(j - 1024);
        else                 row = (j == 17408) ? ROW_ZERO : ROW_ONE;
        out_off[idx] = row * 128u;
    }
}

// Once per launch (after spikes): classify axons.
//  j<1024 -> spike_list + fill M0 entry from spikes t=0
//  buffer -> inverse table inv[row][.] (consumers of pool row)
//  ones   -> 1.0f in both M buffers; zeros -> 0.0f in M1 (M0 zeroed in init)
__global__ void setup_kernel(const int* __restrict__ axon,
                             const unsigned char* __restrict__ Pb,
                             float* __restrict__ M0,
                             float* __restrict__ M1,
                             uint32_t* __restrict__ inv,
                             uint32_t* __restrict__ inv_cnt,
                             uint32_t* __restrict__ spike_list,
                             uint32_t* __restrict__ spike_cnt) {
    int ca = blockIdx.x * 256 + threadIdx.x;        // 64 blocks -> 16384
    int j  = axon[ca];
    if (j < 1024) {
        uint32_t pos = atomicAdd(spike_cnt, 1u);
        spike_list[pos] = (uint32_t)ca | ((uint32_t)j << 14);
        const unsigned char* src = Pb + (size_t)j * 128;    // t=0 spike row
        float* dst = M0 + (size_t)ca * 128;
        #pragma unroll
        for (int q = 0; q < 8; ++q) {
            uint4 v = *(const uint4*)(src + q * 16);
            const unsigned char* pb = (const unsigned char*)&v;
            float4 f0, f1;
            f0.x = (float)pb[0];  f0.y = (float)pb[1];
            f0.z = (float)pb[2];  f0.w = (float)pb[3];
            f1.x = (float)pb[4];  f1.y = (float)pb[5];
            f1.z = (float)pb[6];  f1.w = (float)pb[7];
            *(float4*)(dst + q * 16)     = f0;
            *(float4*)(dst + q * 16 + 4) = f1;
            uint4 v2 = *(const uint4*)(src + q * 16 + 8);
            (void)v2;
            const unsigned char* pc = pb + 8;
            float4 g0, g1;
            g0.x = (float)pc[0];  g0.y = (float)pc[1];
            g0.z = (float)pc[2];  g0.w = (float)pc[3];
            g1.x = (float)pc[4];  g1.y = (float)pc[5];
            g1.z = (float)pc[6];  g1.w = (float)pc[7];
            *(float4*)(dst + q * 16 + 8)  = g0;
            *(float4*)(dst + q * 16 + 12) = g1;
        }
    } else if (j < 17408) {
        int row = j - 1024;                       // = c_src*256 + n
        uint32_t pos = atomicAdd(&inv_cnt[row], 1u);
        if (pos < 16) inv[row * 16 + pos] = (uint32_t)ca;
    } else if (j == 17409) {
        float* d0 = M0 + (size_t)ca * 128;
        float* d1 = M1 + (size_t)ca * 128;
        float4 one = {1.0f, 1.0f, 1.0f, 1.0f};
        #pragma unroll
        for (int q = 0; q < 32; ++q) { *(float4*)(d0 + q*4) = one; *(float4*)(d1 + q*4) = one; }
    } else {  // 17408: zeros row -> M1 must be 0.0 (M0 zeroed by init)
        float* d1 = M1 + (size_t)ca * 128;
        float4 z = {0.0f, 0.0f, 0.0f, 0.0f};
        #pragma unroll
        for (int q = 0; q < 32; ++q) *(float4*)(d1 + q*4) = z;
    }
}

// One cycle. 544 blocks x 256 thr: blocks [0,512) main = (c, bgq), blocks
// [512,544) = spike-axon filler for M_next (cycle t+1).
// Main wave w: nh = w&1 (n-half), bg = bgq*2 + (w>>1) (b-oct). Lane owns an
// n-pair. Per a: 2 uniform float4 M loads (s_load, group-of-8 prefetch) +
// 1 per-lane dwordx2 weight load (vmcnt pipeline) + 16 v_fmac(acc, s_m, v_w).
// Zero DS. Epilogue: memb RMW, fired bytes -> Pb, fired floats inverse-
// scattered into M_next (consumers of this row).
__global__ __launch_bounds__(256, 2) void core_kernel(
    const unsigned char* __restrict__ Pb,
    unsigned char* __restrict__ Pw,
    const float* __restrict__ WT,
    const float* __restrict__ M_cur,
    float* __restrict__ M_next,
    float* __restrict__ memb,
    const float* __restrict__ thresholds,
    const uint32_t* __restrict__ inv,
    const uint32_t* __restrict__ inv_cnt,
    const uint32_t* __restrict__ spike_list,
    const uint32_t* __restrict__ spike_cnt,
    uint32_t wbyte_base,
    const uint32_t* __restrict__ out_off_prev,
    float* __restrict__ d_out,
    int do_out,
    int t_next)         // 0 = no spike fill (last cycle)
{
    int tid = threadIdx.x;
    int bx  = blockIdx.x;

    if (bx >= 512) {                      // ---- spike-axon filler blocks ----
        if (t_next > 0) {
            int nsp = (int)*spike_cnt;
            int ntask = nsp * 8;
            for (int task = (bx - 512) * 256 + tid; task < ntask; task += 32 * 256) {
                int e  = task >> 3;
                int ch = task & 7;
                uint32_t sl = spike_list[e];
                int ca = (int)(sl & 16383u);
                int j  = (int)(sl >> 14);
                const unsigned char* src = Pb + ((size_t)t_next * 1024 + j) * 128 + ch * 16;
                uint4 v = *(const uint4*)src;
                const unsigned char* pb = (const unsigned char*)&v;
                float* dst = M_next + (size_t)ca * 128 + ch * 16;
                #pragma unroll
                for (int q = 0; q < 4; ++q) {
                    float4 f;
                    f.x = (float)pb[4*q+0]; f.y = (float)pb[4*q+1];
                    f.z = (float)pb[4*q+2]; f.w = (float)pb[4*q+3];
                    *(float4*)(dst + 4*q) = f;
                }
            }
        }
        return;
    }

    // fused out-update for the PREVIOUS cycle (reads current READ parity)
    if (do_out && bx == 0 && tid < BB) {
        #pragma unroll
        for (int o = 0; o < NOUT; ++o) {
            uint32_t off = out_off_prev[o];
            d_out[tid * NOUT + o] += (float)Pb[off + (uint32_t)tid];
        }
    }

    // decode: 512 = 8 xcd * 8 c-local * 8 bgq  (c grouped per XCD for L2)
    int c   = (bx & 7) * 8 + ((bx >> 3) & 7);
    int bgq = bx >> 6;                  // 0..7
    int lane = tid & 63;
    int wid  = __builtin_amdgcn_readfirstlane(tid >> 6);
    int nh   = wid & 1;
    int bg   = bgq * 2 + (wid >> 1);    // 0..15
    int n0   = nh * 128;

    const float4* Mb4 = (const float4*)(M_cur + ((size_t)c * 256) * 128 + bg * 8);
    const float*  wtp = WT + (size_t)c * 65536 + n0 + lane * 2;

    float acc0[8], acc1[8];             // [b]: rows n0+2*lane, n0+2*lane+1
    #pragma unroll
    for (int b = 0; b < 8; ++b) { acc0[b] = 0.0f; acc1[b] = 0.0f; }

    // ---- Hot loop: groups of 8 a; exact ascending-a chain ----
    for (int ag = 0; ag < 256; ag += 8) {
        float4 m0[8], m1[8];
        v2f    wg[8];
        #pragma unroll
        for (int i = 0; i < 8; ++i) {
            m0[i] = Mb4[(size_t)(ag + i) * 32];        // uniform -> s_load
            m1[i] = Mb4[(size_t)(ag + i) * 32 + 1];
            wg[i] = *(const v2f*)(wtp + (size_t)(ag + i) * 256);
        }
        #pragma unroll
        for (int i = 0; i < 8; ++i) {
            float w0 = wg[i].x, w1 = wg[i].y;
            const float mm[8] = {m0[i].x, m0[i].y, m0[i].z, m0[i].w,
                                 m1[i].x, m1[i].y, m1[i].z, m1[i].w};
            #pragma unroll
            for (int b = 0; b < 8; ++b) {
                acc0[b] = fmaf(w0, mm[b], acc0[b]);
                acc1[b] = fmaf(w1, mm[b], acc1[b]);
            }
        }
    }

    // ---- Epilogue: memb RMW + fired bytes + M_next inverse-scatter ----
    float thr = thresholds[c];

#define EPI(NJ, ACC)                                                          \
    { int n   = n0 + lane * 2 + NJ;                                           \
      int row = c * 256 + n;                                                  \
      size_t mi = (size_t)row * 128 + bg * 8;                                 \
      float4 p0 = *(const float4*)(memb + mi);                                \
      float4 p1 = *(const float4*)(memb + mi + 4);                            \
      float vv[8];                                                            \
      vv[0] = p0.x + ACC[0]; vv[1] = p0.y + ACC[1];                           \
      vv[2] = p0.z + ACC[2]; vv[3] = p0.w + ACC[3];                           \
      vv[4] = p1.x + ACC[4]; vv[5] = p1.y + ACC[5];                           \
      vv[6] = p1.z + ACC[6]; vv[7] = p1.w + ACC[7];                           \
      uint32_t flo = 0, fhi = 0;                                              \
      float st[8], ff[8];                                                     \
      _Pragma("unroll")                                                       \
      for (int k = 0; k < 8; ++k) {                                           \
          bool f = vv[k] > thr;                                               \
          st[k] = f ? 0.0f : vv[k];                                           \
          ff[k] = f ? 1.0f : 0.0f;                                            \
          if (k < 4) flo |= (f ? 1u : 0u) << (8 * k);                         \
          else       fhi |= (f ? 1u : 0u) << (8 * (k - 4));                   \
      }                                                                       \
      float4 s0 = {st[0], st[1], st[2], st[3]};                               \
      float4 s1 = {st[4], st[5], st[6], st[7]};                               \
      *(float4*)(memb + mi)     = s0;                                         \
      *(float4*)(memb + mi + 4) = s1;                                         \
      uint2 fb = {flo, fhi};                                                  \
      *(uint2*)(Pw + wbyte_base + mi) = fb;                                   \
      int cnt = (int)inv_cnt[row];                                            \
      float4 q0 = {ff[0], ff[1], ff[2], ff[3]};                               \
      float4 q1 = {ff[4], ff[5], ff[6], ff[7]};                               \
      for (int k = 0; k < cnt; ++k) {                                         \
          int ca = (int)inv[row * 16 + k];                                    \
          float* dst = M_next + (size_t)ca * 128 + bg * 8;                    \
          *(float4*)dst       = q0;                                           \
          *(float4*)(dst + 4) = q1;                                           \
      } }

    EPI(0, acc0)
    EPI(1, acc1)
#undef EPI
}

__global__ void tail_kernel(const unsigned char* __restrict__ Pb,
                            const uint32_t* __restrict__ out_off31,
                            float* __restrict__ d_out) {
    int tid = threadIdx.x;
    if (tid < BB) {
        #pragma unroll
        for (int o = 0; o < NOUT; ++o) {
            uint32_t off = out_off31[o];
            d_out[tid * NOUT + o] += (float)Pb[off + (uint32_t)tid];
        }
    }
}

extern "C" void kernel_launch(void* const* d_in, const int* in_sizes, int n_in,
                              void* d_out_, int out_size, void* d_ws, size_t ws_size,
                              hipStream_t stream) {
    const float* x          = (const float*)d_in[0];
    const float* W          = (const float*)d_in[1];
    const float* thresholds = (const float*)d_in[2];
    const int*   axon       = (const int*)d_in[3];
    const int*   outsrc     = (const int*)d_in[4];
    // d_in[5] = cycles; fixed instance -> 32.

    if (ws_size < (size_t)80 * 1024 * 1024) return;

    unsigned char* ws         = (unsigned char*)d_ws;
    unsigned char* Pb         = ws;                                     // 8.4 MB
    float*         WT         = (float*)(ws + (size_t)(16u << 20));     // 16 MiB
    uint32_t*      out_off    = (uint32_t*)(ws + (size_t)(34u << 20));
    float*         memb       = (float*)(ws + (size_t)(36u << 20));     // 8 MiB
    float*         M0         = (float*)(ws + (size_t)(48u << 20));     // 8 MiB
    float*         M1         = (float*)(ws + (size_t)(56u << 20));     // 8 MiB
    uint32_t*      inv        = (uint32_t*)(ws + (size_t)(64u << 20));  // 1 MiB
    uint32_t*      inv_cnt    = (uint32_t*)(ws + (size_t)(66u << 20));  // 64 KiB
    uint32_t*      spike_list = (uint32_t*)(ws + (size_t)(67u << 20));  // 64 KiB
    uint32_t*      spike_cnt  = (uint32_t*)(ws + (size_t)(68u << 20));
    float*         out        = (float*)d_out_;

    init_kernel<<<2048, 256, 0, stream>>>(Pb, memb, M0, inv_cnt, spike_cnt, out);
    spikes_kernel<<<1024, 256, 0, stream>>>(x, Pb);
    wt_kernel<<<4096, 256, 0, stream>>>(W, WT);
    outoff_kernel<<<1, 256, 0, stream>>>(outsrc, out_off);
    setup_kernel<<<64, 256, 0, stream>>>(axon, Pb, M0, M1, inv, inv_cnt,
                                         spike_list, spike_cnt);

    float* Mbuf[2] = {M0, M1};
    for (int t = 0; t < CYCLES; ++t) {
        uint32_t wrow = ((t & 1) == 0) ? ROW_B : ROW_A;   // write parity
        const uint32_t* oprev = out_off + (t > 0 ? (t - 1) * NOUT : 0);
        core_kernel<<<544, 256, 0, stream>>>(
            Pb, Pb, WT, Mbuf[t & 1], Mbuf[(t + 1) & 1], memb, thresholds,
            inv, inv_cnt, spike_list, spike_cnt,
            wrow * 128u, oprev, out, t > 0 ? 1 : 0,
            (t < CYCLES - 1) ? (t + 1) : 0);
    }
    tail_kernel<<<1, 128, 0, stream>>>(Pb, out_off + 31 * NOUT, out);
}